// Round 1
// baseline (305.663 us; speedup 1.0000x reference)
//
#include <hip/hip_runtime.h>
#include <hip/hip_bf16.h>

#define T_SEQ 2048
#define BATCH 2
#define CDIM  2048
#define NH    16
#define NKV   4
#define DH    128

typedef __attribute__((ext_vector_type(8))) short bfrag;   // 8 bf16 (4 VGPRs)
typedef __attribute__((ext_vector_type(4))) float ffrag;   // 4 f32 acc
typedef __hip_bfloat16 bf16;

__device__ __forceinline__ void gll16(const bf16* __restrict__ g, bf16* lds) {
    __builtin_amdgcn_global_load_lds((const __attribute__((address_space(1))) void*)g,
                                     (__attribute__((address_space(3))) void*)lds, 16, 0, 0);
}

template<int N> __device__ __forceinline__ void vmw() {
    static_assert(N >= 0 && N <= 6, "vmcnt range");
    if constexpr      (N == 0) asm volatile("s_waitcnt vmcnt(0)" ::: "memory");
    else if constexpr (N == 1) asm volatile("s_waitcnt vmcnt(1)" ::: "memory");
    else if constexpr (N == 2) asm volatile("s_waitcnt vmcnt(2)" ::: "memory");
    else if constexpr (N == 3) asm volatile("s_waitcnt vmcnt(3)" ::: "memory");
    else if constexpr (N == 4) asm volatile("s_waitcnt vmcnt(4)" ::: "memory");
    else if constexpr (N == 5) asm volatile("s_waitcnt vmcnt(5)" ::: "memory");
    else                       asm volatile("s_waitcnt vmcnt(6)" ::: "memory");
}
// raw barrier with compiler code-motion fences (no auto vmcnt(0) drain)
__device__ __forceinline__ void barx() {
    asm volatile("" ::: "memory");
    __builtin_amdgcn_s_barrier();
    asm volatile("" ::: "memory");
}

// steady-state vmcnt after phase p (issue order B0..B3,A0..; consumption prefix 5,6,...)
constexpr int sv_c(int P, int L, int LPP, int p) {
    return p == P - 1 ? L - 5 : (L - 5) + (p + 1) * (LPP - 1);
}
// drain vmcnt on the last K-tile (no new issues)
constexpr int dv_c(int L, int p) { int r = L - 5 - (p + 1); return r < 0 ? 0 : r; }

// ---------------- merged fp32 -> bf16 cast of all 4 inputs ----------------
struct bf16x4 { bf16 a, b, c, d; };
#define N4_X   (BATCH * T_SEQ * CDIM / 4)
#define N4_WQ  (CDIM * CDIM / 4)
#define N4_WKV (2 * NKV * DH * CDIM / 4)
#define N4_WP  (CDIM * CDIM / 4)
__global__ __launch_bounds__(256) void cast_all(
    const float* __restrict__ x, const float* __restrict__ wq,
    const float* __restrict__ wkv, const float* __restrict__ wp,
    bf16* __restrict__ xb, bf16* __restrict__ wqb, bf16* __restrict__ wkvb, bf16* __restrict__ wpb)
{
    int j = blockIdx.x * 256 + threadIdx.x;
    const float* s; bf16* d;
    if (j < N4_X) { s = x; d = xb; }
    else {
        j -= N4_X;
        if (j < N4_WQ) { s = wq; d = wqb; }
        else {
            j -= N4_WQ;
            if (j < N4_WKV) { s = wkv; d = wkvb; }
            else { j -= N4_WKV; if (j >= N4_WP) return; s = wp; d = wpb; }
        }
    }
    float4 f = ((const float4*)s)[j];
    bf16x4 o{__float2bfloat16(f.x), __float2bfloat16(f.y),
             __float2bfloat16(f.z), __float2bfloat16(f.w)};
    ((bf16x4*)d)[j] = o;
}

// ---------------- 8-wave phase-interleaved GEMM (T2+T3+T4+T5) ----------------
// Tile BM x 256, BK=64, 8 waves (2M x 4N), per-wave BM/2 x 64 output.
// Wave m-frag f -> tile row f*32 + wm*16 (interleaved so phase p consumes exactly
// A stage-load p). LDS rows are 128B (64 bf16); swizzle: 16B-slot ^= (row&7),
// applied by pre-swizzling the global SOURCE col (global_load_lds writes linearly)
// and on the ds_read address -> fragment reads are 2-way (free).
// Counted vmcnt: issue order per K-tile is B0..B3,A0..A(LA-1), 2-3 per phase, into
// buf^1 while computing buf; boundary wait leaves the not-yet-needed A-loads in
// flight (never vmcnt(0) in the main loop).
template<int BM, int MODE>
__device__ __forceinline__ void gemm8_body(
    const bf16* __restrict__ A, const bf16* __restrict__ W, int m0, int n0,
    bf16* __restrict__ out0, bf16* __restrict__ out1, float* __restrict__ outf,
    bf16* __restrict__ sA, bf16* __restrict__ sB)
{
    constexpr int MREP = BM / 32;        // m-frags per wave (8 or 4)
    constexpr int P    = MREP / 2;       // phases per K-tile (4 or 2), 16 MFMA each
    constexpr int LA   = BM / 64;        // A stage loads per K-tile (4 or 2)
    constexpr int L    = LA + 4;         // total stage loads per K-tile
    constexpr int LPP  = L / P;          // loads issued per phase (2 or 3)
    constexpr int NT   = CDIM / 64;      // 32 K-tiles
    constexpr int ASZ  = BM * 64;        // elems per A buffer
    constexpr int BSZ  = 256 * 64;

    const int lane = threadIdx.x & 63;
    const int w    = threadIdx.x >> 6;
    const int wm   = w >> 2, wn = w & 3;
    const int lr   = lane & 15, quad = lane >> 4;
    const int srow = lane >> 3;                    // staging row-in-8
    const int scol = ((lane & 7) ^ srow) << 3;     // inverse-swizzled source col

    const bf16* Ag[LA];
    const bf16* Bg[4];
    #pragma unroll
    for (int j = 0; j < LA; ++j) Ag[j] = A + (size_t)(m0 + j * 64 + w * 8 + srow) * CDIM + scol;
    #pragma unroll
    for (int j = 0; j < 4; ++j)  Bg[j] = W + (size_t)(n0 + j * 64 + w * 8 + srow) * CDIM + scol;

    ffrag acc[MREP][4] = {};

    // prologue: stage K-tile 0 into buf 0 (FIFO order B0..B3, A0..)
    #pragma unroll
    for (int j = 0; j < 4; ++j)  gll16(Bg[j], sB + j * 4096 + w * 512);
    #pragma unroll
    for (int j = 0; j < LA; ++j) gll16(Ag[j], sA + j * 4096 + w * 512);
    vmw<L - 5>();                                  // need B0..B3 + A0 (prefix 5)
    barx();

    for (int t = 0; t < NT; ++t) {
        const int cur = t & 1;
        const bool last = (t == NT - 1);
        const int knext = (t + 1) * 64;
        bf16* sAc = sA + cur * ASZ;
        bf16* sBc = sB + cur * BSZ;
        bf16* sAn = sA + (cur ^ 1) * ASZ;
        bf16* sBn = sB + (cur ^ 1) * BSZ;
        bfrag bgr[2][4];

#define PHASE(pp)                                                                          \
        {                                                                                  \
            if (pp == 0) {                                                                 \
                _Pragma("unroll")                                                          \
                for (int g = 0; g < 4; ++g) {                                              \
                    const int br = (wn * 64 + g * 16 + lr) * 64;                           \
                    bgr[0][g] = *(const bfrag*)&sBc[br + ((quad ^ (lr & 7)) << 3)];        \
                    bgr[1][g] = *(const bfrag*)&sBc[br + (((4 | quad) ^ (lr & 7)) << 3)];  \
                }                                                                          \
            }                                                                              \
            bfrag af0[2], af1[2];                                                          \
            _Pragma("unroll")                                                              \
            for (int f2 = 0; f2 < 2; ++f2) {                                               \
                const int ar = ((2 * pp + f2) * 32 + wm * 16 + lr) * 64;                   \
                af0[f2] = *(const bfrag*)&sAc[ar + ((quad ^ (lr & 7)) << 3)];              \
                af1[f2] = *(const bfrag*)&sAc[ar + (((4 | quad) ^ (lr & 7)) << 3)];        \
            }                                                                              \
            if (!last) {                                                                   \
                _Pragma("unroll")                                                          \
                for (int l = pp * LPP; l < (pp + 1) * LPP; ++l) {                          \
                    if (l < 4) gll16(Bg[l] + knext, sBn + l * 4096 + w * 512);             \
                    else       gll16(Ag[l - 4] + knext, sAn + (l - 4) * 4096 + w * 512);   \
                }                                                                          \
            }                                                                              \
            barx();                                                                        \
            __builtin_amdgcn_s_setprio(1);                                                 \
            _Pragma("unroll")                                                              \
            for (int f2 = 0; f2 < 2; ++f2)                                                 \
                _Pragma("unroll")                                                          \
                for (int g = 0; g < 4; ++g) {                                              \
                    acc[2 * pp + f2][g] = __builtin_amdgcn_mfma_f32_16x16x32_bf16(         \
                        af0[f2], bgr[0][g], acc[2 * pp + f2][g], 0, 0, 0);                 \
                    acc[2 * pp + f2][g] = __builtin_amdgcn_mfma_f32_16x16x32_bf16(         \
                        af1[f2], bgr[1][g], acc[2 * pp + f2][g], 0, 0, 0);                 \
                }                                                                          \
            __builtin_amdgcn_s_setprio(0);                                                 \
            if (!last) vmw<sv_c(P, L, LPP, pp)>();                                         \
            else if (pp != P - 1) vmw<dv_c(L, pp)>();                                      \
            barx();                                                                        \
        }

        PHASE(0)
        PHASE(1)
        if constexpr (P == 4) {
            PHASE(2)
            PHASE(3)
        }
#undef PHASE
    }

    #pragma unroll
    for (int f = 0; f < MREP; ++f) {
        #pragma unroll
        for (int g = 0; g < 4; ++g) {
            #pragma unroll
            for (int i = 0; i < 4; ++i) {
                const int m = m0 + f * 32 + wm * 16 + quad * 4 + i;
                const int n = n0 + wn * 64 + g * 16 + lr;
                const float v = acc[f][g][i];
                if constexpr (MODE == 0) {
                    int b = m >> 11, tt = m & (T_SEQ - 1);
                    int h = n >> 7, d = n & (DH - 1);
                    out0[(((size_t)(b * NH + h) * T_SEQ + tt) << 7) + d] = __float2bfloat16(v);
                } else if constexpr (MODE == 1) {
                    int b = m >> 11, tt = m & (T_SEQ - 1);
                    if (n < NKV * DH) {
                        int h = n >> 7, d = n & (DH - 1);
                        out0[(((size_t)(b * NKV + h) * T_SEQ + tt) << 7) + d] = __float2bfloat16(v);
                    } else {
                        int n2 = n - NKV * DH;
                        int h = n2 >> 7, d = n2 & (DH - 1);
                        out1[(((size_t)(b * NKV + h) * DH + d) << 11) + tt] = __float2bfloat16(v);
                    }
                } else {
                    outf[(size_t)m * CDIM + n] = v;
                }
            }
        }
    }
}

__global__ __launch_bounds__(512, 2) void gemm_qkv(
    const bf16* __restrict__ A, const bf16* __restrict__ Wq, const bf16* __restrict__ Wkv,
    bf16* __restrict__ q, bf16* __restrict__ k, bf16* __restrict__ vt)
{
    __shared__ __align__(16) bf16 sA[2 * 256 * 64];   // 64 KiB
    __shared__ __align__(16) bf16 sB[2 * 256 * 64];   // 64 KiB
    const int bid = blockIdx.x;                       // 192 blocks, 192%8==0
    const int sb = (bid & 7) * 24 + (bid >> 3);       // bijective XCD swizzle
    const int mt = sb & 15, nt = sb >> 4;             // 16 m-tiles x 12 n-tiles
    if (nt < 8) gemm8_body<256, 0>(A, Wq,  mt * 256, nt * 256,       q, nullptr, nullptr, sA, sB);
    else        gemm8_body<256, 1>(A, Wkv, mt * 256, (nt - 8) * 256, k, vt,      nullptr, sA, sB);
}

__global__ __launch_bounds__(512, 2) void gemm_proj(
    const bf16* __restrict__ A, const bf16* __restrict__ W, float* __restrict__ outf)
{
    __shared__ __align__(16) bf16 sA[2 * 128 * 64];   // 32 KiB
    __shared__ __align__(16) bf16 sB[2 * 256 * 64];   // 64 KiB
    const int bid = blockIdx.x;                       // 256 blocks = 1/CU
    const int sb = (bid & 7) * 32 + (bid >> 3);
    const int mt = sb & 31, nt = sb >> 5;             // 32 m-tiles x 8 n-tiles
    gemm8_body<128, 2>(A, W, mt * 128, nt * 256, nullptr, nullptr, outf, sA, sB);
    if (blockIdx.x == 0 && threadIdx.x == 0)
        outf[(size_t)BATCH * T_SEQ * CDIM] = 0.0f;    // reference's second output: 0.0
}

// ---------------- RMSNorm + rotary, q and k fused in one launch ----------------
#define QROWS (BATCH * NH * T_SEQ)
#define KROWS (BATCH * NKV * T_SEQ)
__global__ __launch_bounds__(256) void normrope_k(bf16* __restrict__ qb, bf16* __restrict__ kb) {
    int row = blockIdx.x * 4 + (threadIdx.x >> 6);
    bf16* bufb; int nheads;
    if (row < QROWS) { bufb = qb; nheads = NH; }
    else { row -= QROWS; bufb = kb; nheads = NKV; }
    const int h = (row >> 11) % nheads;            // T = 2^11; angle uses HEAD idx (per ref)
    bf16* p = bufb + (size_t)row * DH;
    const int d = threadIdx.x & 63;
    float x1 = __bfloat162float(p[d]);
    float x2 = __bfloat162float(p[d + 64]);
    float ss = x1 * x1 + x2 * x2;
    #pragma unroll
    for (int off = 32; off; off >>= 1) ss += __shfl_xor(ss, off);
    float r = rsqrtf(ss * (1.0f / 128.0f) + 1.1920929e-07f);
    x1 *= r; x2 *= r;
    float freq = (d < 32) ? exp2f(-10.0f * (float)d * (1.0f / 31.0f)) : 0.0f;
    float th = (float)h * freq;
    float c, s;
    __sincosf(th, &s, &c);
    p[d]      = __float2bfloat16(x1 * c + x2 * s);
    p[d + 64] = __float2bfloat16(-x1 * s + x2 * c);
}

// ---------------- Flash attention v5: 8 waves, even/odd chunk groups ----------------
// Static-max softmax (RMS-normed q,k => |score*scale| <= 11.32; exp(s-16) exact).
// Block = 512 thr: group g = waves 0-3 / 4-7; both groups cover the same 128 q-rows
// (wave wl -> rows qb*128 + wl*32, two 16-row tiles) but disjoint 32-key chunks
// (abs chunk 2c+g). Partial (O, l) add linearly (static max) -> fp32 LDS merge.
// Pass pairing (p, 15-p) => uniform 34 group-chunks/block. All LDS arrays are
// unpadded with XOR-chunk swizzle => every access <=2-way (free).
__global__ __launch_bounds__(512, 2) void attn_k(const bf16* __restrict__ Q, const bf16* __restrict__ K,
                                                 const bf16* __restrict__ VT, bf16* __restrict__ Y)
{
    const int lane = threadIdx.x & 63;
    const int w = threadIdx.x >> 6;          // 0..7
    const int g = w >> 2, wl = w & 3;
    const int p = blockIdx.x, h = blockIdx.y, b = blockIdx.z;
    const int lr = lane & 15, quad = lane >> 4, lk = quad * 8;
    const bf16* Qb = Q  + (size_t)(b * NH  + h)        * T_SEQ * DH;
    const bf16* Kb = K  + (size_t)(b * NKV + (h >> 2)) * T_SEQ * DH;
    const bf16* Vb = VT + (size_t)(b * NKV + (h >> 2)) * DH * T_SEQ;

    __shared__ __align__(16) union ShmU {
        struct { bf16 SK[2][32 * 128]; bf16 SV[2][128 * 32]; bf16 SP[8][2][16 * 32]; } s;
        ffrag MRG[9 * 4 * 64];               // 36864 B merge area (aliases SK/SV/SP)
    } shm;
    bf16* SKg = shm.s.SK[g];
    bf16* SVg = shm.s.SV[g];

    // staging coords: K chunk 32(keys)x128, V chunk 128(d)x32(keys), per group
    const int k_r0 = wl * 8 + (lane >> 4);   // + j*4
    const int k_ch = lane & 15;
    const int v_r0 = wl * 32 + (lane >> 2);  // + j*16
    const int v_ch = lane & 3;
    const int vsw = (lr + (lr >> 2)) & 3;    // SV read swizzle (row = dt*16+lr)
    const int prow_r = ((lr & 3) << 2) | (lr >> 2);      // P physical row for read
    const int psw = (prow_r + (prow_r >> 2)) & 3;
    const float scale = 0.08838834764831845f;            // 1/sqrt(128)

    for (int pass = 0; pass < 2; ++pass) {
        const int qb = pass ? (15 - p) : p;
        const int nc = 2 * (qb + 1);         // 32-key chunks for THIS group
        const int q0 = qb * 128 + wl * 32;

        bfrag qf[2][4];
        #pragma unroll
        for (int t = 0; t < 2; ++t)
            #pragma unroll
            for (int dc = 0; dc < 4; ++dc)
                qf[t][dc] = *(const bfrag*)(Qb + (size_t)(q0 + t * 16 + lr) * DH + dc * 32 + lk);

        float lp[2][4] = {};
        ffrag o[2][8] = {};

        bfrag kr[2], vr[2];                  // prefetch chunk 0 (abs chunk g)
        {
            const int b0 = g * 32;
            #pragma unroll
            for (int j = 0; j < 2; ++j) {
                kr[j] = *(const bfrag*)(Kb + (size_t)(b0 + k_r0 + j * 4) * DH + k_ch * 8);
                vr[j] = *(const bfrag*)(Vb + (size_t)(v_r0 + j * 16) * T_SEQ + b0 + v_ch * 8);
            }
        }

        for (int c = 0; c < nc; ++c) {
            const int base = c * 64 + g * 32;
            __syncthreads();                 // all waves done reading SK/SV (and MRG)
            #pragma unroll
            for (int j = 0; j < 2; ++j) {
                int krow = k_r0 + j * 4;
                *(bfrag*)&SKg[krow * 128 + ((k_ch ^ (krow & 15))) * 8] = kr[j];
                int vrow = v_r0 + j * 16;
                *(bfrag*)&SVg[vrow * 32 + ((v_ch ^ ((vrow + (vrow >> 2)) & 3))) * 8] = vr[j];
            }
            if (c + 1 < nc) {                // prefetch next; stays in flight across barrier
                const int nb = base + 64;
                #pragma unroll
                for (int j = 0; j < 2; ++j) {
                    kr[j] = *(const bfrag*)(Kb + (size_t)(nb + k_r0 + j * 4) * DH + k_ch * 8);
                    vr[j] = *(const bfrag*)(Vb + (size_t)(v_r0 + j * 16) * T_SEQ + nb + v_ch * 8);
                }
            }
            __syncthreads();                 // staged data visible

            // QK^T: each kf feeds both row-tiles
            ffrag s2[2][2] = {};
            #pragma unroll
            for (int kt = 0; kt < 2; ++kt)
                #pragma unroll
                for (int dc = 0; dc < 4; ++dc) {
                    bfrag kf = *(const bfrag*)&SKg[(kt * 16 + lr) * 128 + (((dc << 2) | quad) ^ lr) * 8];
                    s2[0][kt] = __builtin_amdgcn_mfma_f32_16x16x32_bf16(qf[0][dc], kf, s2[0][kt], 0, 0, 0);
                    s2[1][kt] = __builtin_amdgcn_mfma_f32_16x16x32_bf16(qf[1][dc], kf, s2[1][kt], 0, 0, 0);
                }

            // softmax numerator (static max); P -> LDS, rows 4x4-transposed, chunks swizzled
            const bool maskc = (c >= 2 * qb);
            #pragma unroll
            for (int t = 0; t < 2; ++t)
                #pragma unroll
                for (int kt = 0; kt < 2; ++kt) {
                    const int col = base + kt * 16 + lr;
                    #pragma unroll
                    for (int i = 0; i < 4; ++i) {
                        const int row = q0 + t * 16 + quad * 4 + i;
                        float e = (!maskc || col <= row) ? __expf(fmaf(s2[t][kt][i], scale, -16.0f)) : 0.0f;
                        lp[t][i] += e;
                        const int pr = i * 4 + quad;
                        const int pc = (kt * 2 + (lr >> 3)) ^ ((quad + i) & 3);
                        shm.s.SP[w][t][pr * 32 + pc * 8 + (lr & 7)] = __float2bfloat16(e);
                    }
                }

            // P.V: each vf feeds both row-tiles (per-wave SP: lgkmcnt handles RAW)
            bfrag pf0 = *(const bfrag*)&shm.s.SP[w][0][prow_r * 32 + ((quad ^ psw)) * 8];
            bfrag pf1 = *(const bfrag*)&shm.s.SP[w][1][prow_r * 32 + ((quad ^ psw)) * 8];
            #pragma unroll
            for (int dt = 0; dt < 8; ++dt) {
                bfrag vf = *(const bfrag*)&SVg[(dt * 16 + lr) * 32 + ((quad ^ vsw)) * 8];
                o[0][dt] = __builtin_amdgcn_mfma_f32_16x16x32_bf16(pf0, vf, o[0][dt], 0, 0, 0);
                o[1][dt] = __builtin_amdgcn_mfma_f32_16x16x32_bf16(pf1, vf, o[1][dt], 0, 0, 0);
            }
        }

        // merge groups (fp32, two rounds to fit LDS) + epilogue by group 0
        __syncthreads();
        #pragma unroll
        for (int t = 0; t < 2; ++t) {
            if (g == 1) {
                #pragma unroll
                for (int d = 0; d < 8; ++d) shm.MRG[(d * 4 + wl) * 64 + lane] = o[t][d];
                ffrag l4 = {lp[t][0], lp[t][1], lp[t][2], lp[t][3]};
                shm.MRG[(8 * 4 + wl) * 64 + lane] = l4;
            }
            __syncthreads();
            if (g == 0) {
                #pragma unroll
                for (int d = 0; d < 8; ++d) o[t][d] += shm.MRG[(d * 4 + wl) * 64 + lane];
                ffrag l4 = shm.MRG[(8 * 4 + wl) * 64 + lane];
                float inv[4];
                #pragma unroll
                for (int i = 0; i < 4; ++i) {
                    float l = lp[t][i] + l4[i];
                    #pragma unroll
                    for (int off = 1; off < 16; off <<= 1) l += __shfl_xor(l, off);
                    inv[i] = 1.0f / l;
                }
                #pragma unroll
                for (int dt = 0; dt < 8; ++dt)
                    #pragma unroll
                    for (int i = 0; i < 4; ++i) {
                        int row = q0 + t * 16 + quad * 4 + i;
                        Y[((size_t)(b * T_SEQ) + row) * CDIM + h * DH + dt * 16 + lr] =
                            __float2bfloat16(o[t][dt][i] * inv[i]);
                    }
            }
            __syncthreads();                 // protect MRG before next round / next pass
        }
    }
}

extern "C" void kernel_launch(void* const* d_in, const int* in_sizes, int n_in,
                              void* d_out, int out_size, void* d_ws, size_t ws_size,
                              hipStream_t stream) {
    const float* x     = (const float*)d_in[0];
    const float* Wq    = (const float*)d_in[1];
    const float* Wkv   = (const float*)d_in[2];
    const float* Wproj = (const float*)d_in[3];
    float* out = (float*)d_out;

    char* ws = (char*)d_ws;
    size_t off = 0;
    auto alloc = [&](size_t bytes) { void* p = ws + off; off += (bytes + 255) & ~255ULL; return p; };
    bf16* xb   = (bf16*)alloc((size_t)BATCH * T_SEQ * CDIM * 2);
    bf16* wqb  = (bf16*)alloc((size_t)CDIM * CDIM * 2);
    bf16* wkvb = (bf16*)alloc((size_t)2 * NKV * DH * CDIM * 2);
    bf16* wpb  = (bf16*)alloc((size_t)CDIM * CDIM * 2);
    bf16* qb   = (bf16*)alloc((size_t)BATCH * NH * T_SEQ * DH * 2);
    bf16* kb   = (bf16*)alloc((size_t)BATCH * NKV * T_SEQ * DH * 2);
    bf16* vtb  = (bf16*)alloc((size_t)BATCH * NKV * DH * T_SEQ * 2);
    bf16* y1   = (bf16*)alloc((size_t)BATCH * T_SEQ * CDIM * 2);

    const int total4 = N4_X + N4_WQ + N4_WKV + N4_WP;
    cast_all<<<(total4 + 255) / 256, 256, 0, stream>>>(x, Wq, Wkv, Wproj, xb, wqb, wkvb, wpb);

    gemm_qkv<<<dim3(192), 512, 0, stream>>>(xb, wqb, wkvb, qb, kb, vtb);
    normrope_k<<<(QROWS + KROWS) / 4, 256, 0, stream>>>(qb, kb);
    attn_k<<<dim3(8, NH, BATCH), 512, 0, stream>>>(qb, kb, vtb, y1);
    gemm_proj<<<dim3(256), 512, 0, stream>>>(y1, wpb, out);
}

// Round 2
// 303.223 us; speedup vs baseline: 1.0080x; 1.0080x over previous
//
#include <hip/hip_runtime.h>
#include <hip/hip_bf16.h>

#define T_SEQ 2048
#define BATCH 2
#define CDIM  2048
#define NH    16
#define NKV   4
#define DH    128

typedef __attribute__((ext_vector_type(8))) short bfrag;   // 8 bf16 (4 VGPRs)
typedef __attribute__((ext_vector_type(4))) float ffrag;   // 4 f32 acc
typedef __hip_bfloat16 bf16;

__device__ __forceinline__ void gll16(const bf16* __restrict__ g, bf16* lds) {
    __builtin_amdgcn_global_load_lds((const __attribute__((address_space(1))) void*)g,
                                     (__attribute__((address_space(3))) void*)lds, 16, 0, 0);
}

template<int N> __device__ __forceinline__ void vmw() {
    static_assert(N >= 0 && N <= 12, "vmcnt range");
    if constexpr      (N == 0)  asm volatile("s_waitcnt vmcnt(0)"  ::: "memory");
    else if constexpr (N == 1)  asm volatile("s_waitcnt vmcnt(1)"  ::: "memory");
    else if constexpr (N == 2)  asm volatile("s_waitcnt vmcnt(2)"  ::: "memory");
    else if constexpr (N == 3)  asm volatile("s_waitcnt vmcnt(3)"  ::: "memory");
    else if constexpr (N == 4)  asm volatile("s_waitcnt vmcnt(4)"  ::: "memory");
    else if constexpr (N == 5)  asm volatile("s_waitcnt vmcnt(5)"  ::: "memory");
    else if constexpr (N == 6)  asm volatile("s_waitcnt vmcnt(6)"  ::: "memory");
    else if constexpr (N == 7)  asm volatile("s_waitcnt vmcnt(7)"  ::: "memory");
    else if constexpr (N == 8)  asm volatile("s_waitcnt vmcnt(8)"  ::: "memory");
    else if constexpr (N == 9)  asm volatile("s_waitcnt vmcnt(9)"  ::: "memory");
    else if constexpr (N == 10) asm volatile("s_waitcnt vmcnt(10)" ::: "memory");
    else if constexpr (N == 11) asm volatile("s_waitcnt vmcnt(11)" ::: "memory");
    else                        asm volatile("s_waitcnt vmcnt(12)" ::: "memory");
}
// raw barrier with compiler code-motion fences (no auto vmcnt(0) drain)
__device__ __forceinline__ void barx() {
    asm volatile("" ::: "memory");
    __builtin_amdgcn_s_barrier();
    asm volatile("" ::: "memory");
}

// ---------------- merged fp32 -> bf16 cast of all 4 inputs ----------------
struct bf16x4 { bf16 a, b, c, d; };
#define N4_X   (BATCH * T_SEQ * CDIM / 4)
#define N4_WQ  (CDIM * CDIM / 4)
#define N4_WKV (2 * NKV * DH * CDIM / 4)
#define N4_WP  (CDIM * CDIM / 4)
__global__ __launch_bounds__(256) void cast_all(
    const float* __restrict__ x, const float* __restrict__ wq,
    const float* __restrict__ wkv, const float* __restrict__ wp,
    bf16* __restrict__ xb, bf16* __restrict__ wqb, bf16* __restrict__ wkvb, bf16* __restrict__ wpb)
{
    int j = blockIdx.x * 256 + threadIdx.x;
    const float* s; bf16* d;
    if (j < N4_X) { s = x; d = xb; }
    else {
        j -= N4_X;
        if (j < N4_WQ) { s = wq; d = wqb; }
        else {
            j -= N4_WQ;
            if (j < N4_WKV) { s = wkv; d = wkvb; }
            else { j -= N4_WKV; if (j >= N4_WP) return; s = wp; d = wpb; }
        }
    }
    float4 f = ((const float4*)s)[j];
    bf16x4 o{__float2bfloat16(f.x), __float2bfloat16(f.y),
             __float2bfloat16(f.z), __float2bfloat16(f.w)};
    ((bf16x4*)d)[j] = o;
}

// ---------------- deep-pipelined 8-wave GEMM: BK=32, 4 LDS buffers ----------------
// Tile BM x 256, 8 waves (2M x 4N), per-wave BM/2 x 64 output.
// One phase per K-tile: vmcnt(2L); barrier; 12 ds_read_b128; issue L global_load_lds
// for tile t+3; setprio(1); 32 MFMA; setprio(0).  Prefetch depth 3 => the loads a
// wait needs were issued ~3*1200 cycles earlier (covers HBM-miss latency); loads
// never drained to 0 in the main loop.  WAR safety with the single barrier: the
// prefetch overwrites tile t-1's buffer and is issued after barrier(t), which all
// waves reach only after their tile-(t-1) MFMAs consumed all tile-(t-1) ds_reads.
// LDS layout (per tile buffer): logical [row][k<32] packed as phys [row/2][ (row&1)*32 + k ]
// => 128 B rows = 8 x 16B slots; slot ^= (prow&7) (applied to the global SOURCE for
// staging, since global_load_lds writes linearly, and to the ds_read address)
// => the fragment-read pattern is the measured zero-conflict 8-slot distribution.
template<int BM, int MODE>
__device__ __forceinline__ void gemm32_body(
    const bf16* __restrict__ A, const bf16* __restrict__ W, int m0, int n0,
    bf16* __restrict__ out0, bf16* __restrict__ out1, float* __restrict__ outf,
    bf16* __restrict__ sA, bf16* __restrict__ sB)
{
    constexpr int MREP  = BM / 32;       // m-frags per wave (8 or 4)
    constexpr int LA    = BM / 128;      // A block-loads per tile (2 or 1)
    constexpr int L     = LA + 2;        // loads per tile per wave (4 or 3)
    constexpr int NT    = CDIM / 32;     // 64 K-tiles
    constexpr int DEPTH = 3;             // prefetch distance (4 buffers)
    constexpr int ASZ   = BM * 32;       // elems per A buffer (8K or 4K)
    constexpr int BSZ   = 256 * 32;      // elems per B buffer

    const int tid  = threadIdx.x;
    const int lane = tid & 63;
    const int w    = tid >> 6;
    const int wm   = w >> 2, wn = w & 3;
    const int lr   = lane & 15, quad = lane >> 4;

    // staging source coords (lane's linear LDS slot -> pre-swizzled global addr)
    const int prow_s = tid >> 3;                    // phys row 0..63 per block-load
    const int ls     = (tid & 7) ^ (prow_s & 7);    // logical slot after inverse swizzle
    const int r_s    = 2 * (prow_s & 63) + (ls >> 2);  // logical row 0..127
    const int k0_s   = (ls & 3) * 8;                // k sub-offset 0..24
    const int wbase  = w * 512;                     // wave-uniform LDS dest (elems)

    const bf16* Asrc[LA];
    const bf16* Bsrc[2];
    #pragma unroll
    for (int j = 0; j < LA; ++j) Asrc[j] = A + (size_t)(m0 + j * 128 + r_s) * CDIM + k0_s;
    #pragma unroll
    for (int j = 0; j < 2; ++j)  Bsrc[j] = W + (size_t)(n0 + j * 128 + r_s) * CDIM + k0_s;

    // fragment-read swizzled slot offset (elems)
    const int soff = ((((lr & 1) << 2) | quad) ^ ((lr >> 1) & 7)) << 3;

    ffrag acc[MREP][4] = {};

    // prologue: issue tiles 0..DEPTH-1 into buffers 0..DEPTH-1 (B0,B1,A0[,A1] each)
    #pragma unroll
    for (int tt = 0; tt < DEPTH; ++tt) {
        #pragma unroll
        for (int j = 0; j < 2; ++j)  gll16(Bsrc[j] + tt * 32, sB + tt * BSZ + j * 4096 + wbase);
        #pragma unroll
        for (int j = 0; j < LA; ++j) gll16(Asrc[j] + tt * 32, sA + tt * ASZ + j * 4096 + wbase);
    }

#define GITER(tt, WAITN, PFF)                                                              \
    {                                                                                      \
        vmw<WAITN>();                                                                      \
        barx();                                                                            \
        const int cur = (tt) & 3;                                                          \
        bfrag af[MREP], bg[4];                                                             \
        _Pragma("unroll")                                                                  \
        for (int f = 0; f < MREP; ++f)                                                     \
            af[f] = *(const bfrag*)&sA[cur * ASZ + ((f * 16 + wm * 8 + (lr >> 1)) << 6) + soff]; \
        _Pragma("unroll")                                                                  \
        for (int g = 0; g < 4; ++g)                                                        \
            bg[g] = *(const bfrag*)&sB[cur * BSZ + ((wn * 32 + g * 8 + (lr >> 1)) << 6) + soff]; \
        if (PFF) {                                                                         \
            const int pb = ((tt) + DEPTH) & 3;                                             \
            const size_t ko = (size_t)((tt) + DEPTH) * 32;                                 \
            _Pragma("unroll")                                                              \
            for (int j = 0; j < 2; ++j)                                                    \
                gll16(Bsrc[j] + ko, sB + pb * BSZ + j * 4096 + wbase);                     \
            _Pragma("unroll")                                                              \
            for (int j = 0; j < LA; ++j)                                                   \
                gll16(Asrc[j] + ko, sA + pb * ASZ + j * 4096 + wbase);                     \
        }                                                                                  \
        __builtin_amdgcn_s_setprio(1);                                                     \
        _Pragma("unroll")                                                                  \
        for (int f = 0; f < MREP; ++f)                                                     \
            _Pragma("unroll")                                                              \
            for (int g = 0; g < 4; ++g)                                                    \
                acc[f][g] = __builtin_amdgcn_mfma_f32_16x16x32_bf16(af[f], bg[g], acc[f][g], 0, 0, 0); \
        __builtin_amdgcn_s_setprio(0);                                                     \
    }

    int t = 0;
    for (; t < NT - DEPTH; ++t) GITER(t, 2 * L, true)
    GITER(t, 2 * L, false) ++t;          // t = NT-3: tiles NT-2,NT-1 stay in flight
    GITER(t, L, false)     ++t;          // t = NT-2
    GITER(t, 0, false)                   // t = NT-1: final drain
#undef GITER

    #pragma unroll
    for (int f = 0; f < MREP; ++f) {
        #pragma unroll
        for (int g = 0; g < 4; ++g) {
            #pragma unroll
            for (int i = 0; i < 4; ++i) {
                const int m = m0 + f * 32 + wm * 16 + quad * 4 + i;
                const int n = n0 + wn * 64 + g * 16 + lr;
                const float v = acc[f][g][i];
                if constexpr (MODE == 0) {
                    int b = m >> 11, tt2 = m & (T_SEQ - 1);
                    int h = n >> 7, d = n & (DH - 1);
                    out0[(((size_t)(b * NH + h) * T_SEQ + tt2) << 7) + d] = __float2bfloat16(v);
                } else if constexpr (MODE == 1) {
                    int b = m >> 11, tt2 = m & (T_SEQ - 1);
                    if (n < NKV * DH) {
                        int h = n >> 7, d = n & (DH - 1);
                        out0[(((size_t)(b * NKV + h) * T_SEQ + tt2) << 7) + d] = __float2bfloat16(v);
                    } else {
                        int n2 = n - NKV * DH;
                        int h = n2 >> 7, d = n2 & (DH - 1);
                        out1[(((size_t)(b * NKV + h) * DH + d) << 11) + tt2] = __float2bfloat16(v);
                    }
                } else {
                    outf[(size_t)m * CDIM + n] = v;
                }
            }
        }
    }
}

__global__ __launch_bounds__(512, 2) void gemm_qkv(
    const bf16* __restrict__ A, const bf16* __restrict__ Wq, const bf16* __restrict__ Wkv,
    bf16* __restrict__ q, bf16* __restrict__ k, bf16* __restrict__ vt)
{
    __shared__ __align__(16) bf16 sA[4 * 256 * 32];   // 64 KiB
    __shared__ __align__(16) bf16 sB[4 * 256 * 32];   // 64 KiB
    const int bid = blockIdx.x;                       // 192 blocks, 192%8==0
    const int sb = (bid & 7) * 24 + (bid >> 3);       // bijective XCD swizzle
    const int mt = sb & 15, nt = sb >> 4;             // 16 m-tiles x 12 n-tiles
    if (nt < 8) gemm32_body<256, 0>(A, Wq,  mt * 256, nt * 256,       q, nullptr, nullptr, sA, sB);
    else        gemm32_body<256, 1>(A, Wkv, mt * 256, (nt - 8) * 256, k, vt,      nullptr, sA, sB);
}

__global__ __launch_bounds__(512, 2) void gemm_proj(
    const bf16* __restrict__ A, const bf16* __restrict__ W, float* __restrict__ outf)
{
    __shared__ __align__(16) bf16 sA[4 * 128 * 32];   // 32 KiB
    __shared__ __align__(16) bf16 sB[4 * 256 * 32];   // 64 KiB
    const int bid = blockIdx.x;                       // 256 blocks = 1/CU
    const int sb = (bid & 7) * 32 + (bid >> 3);
    const int mt = sb & 31, nt = sb >> 5;             // 32 m-tiles x 8 n-tiles
    gemm32_body<128, 2>(A, W, mt * 128, nt * 256, nullptr, nullptr, outf, sA, sB);
    if (blockIdx.x == 0 && threadIdx.x == 0)
        outf[(size_t)BATCH * T_SEQ * CDIM] = 0.0f;    // reference's second output: 0.0
}

// ---------------- RMSNorm + rotary, q and k fused in one launch ----------------
#define QROWS (BATCH * NH * T_SEQ)
#define KROWS (BATCH * NKV * T_SEQ)
__global__ __launch_bounds__(256) void normrope_k(bf16* __restrict__ qb, bf16* __restrict__ kb) {
    int row = blockIdx.x * 4 + (threadIdx.x >> 6);
    bf16* bufb; int nheads;
    if (row < QROWS) { bufb = qb; nheads = NH; }
    else { row -= QROWS; bufb = kb; nheads = NKV; }
    const int h = (row >> 11) % nheads;            // T = 2^11; angle uses HEAD idx (per ref)
    bf16* p = bufb + (size_t)row * DH;
    const int d = threadIdx.x & 63;
    float x1 = __bfloat162float(p[d]);
    float x2 = __bfloat162float(p[d + 64]);
    float ss = x1 * x1 + x2 * x2;
    #pragma unroll
    for (int off = 32; off; off >>= 1) ss += __shfl_xor(ss, off);
    float r = rsqrtf(ss * (1.0f / 128.0f) + 1.1920929e-07f);
    x1 *= r; x2 *= r;
    float freq = (d < 32) ? exp2f(-10.0f * (float)d * (1.0f / 31.0f)) : 0.0f;
    float th = (float)h * freq;
    float c, s;
    __sincosf(th, &s, &c);
    p[d]      = __float2bfloat16(x1 * c + x2 * s);
    p[d + 64] = __float2bfloat16(-x1 * s + x2 * c);
}

// ---------------- Flash attention v5: 8 waves, even/odd chunk groups ----------------
// Static-max softmax (RMS-normed q,k => |score*scale| <= 11.32; exp(s-16) exact).
// Block = 512 thr: group g = waves 0-3 / 4-7; both groups cover the same 128 q-rows
// (wave wl -> rows qb*128 + wl*32, two 16-row tiles) but disjoint 32-key chunks
// (abs chunk 2c+g). Partial (O, l) add linearly (static max) -> fp32 LDS merge.
// Pass pairing (p, 15-p) => uniform 34 group-chunks/block. All LDS arrays are
// unpadded with XOR-chunk swizzle => every access <=2-way (free).
__global__ __launch_bounds__(512, 2) void attn_k(const bf16* __restrict__ Q, const bf16* __restrict__ K,
                                                 const bf16* __restrict__ VT, bf16* __restrict__ Y)
{
    const int lane = threadIdx.x & 63;
    const int w = threadIdx.x >> 6;          // 0..7
    const int g = w >> 2, wl = w & 3;
    const int p = blockIdx.x, h = blockIdx.y, b = blockIdx.z;
    const int lr = lane & 15, quad = lane >> 4, lk = quad * 8;
    const bf16* Qb = Q  + (size_t)(b * NH  + h)        * T_SEQ * DH;
    const bf16* Kb = K  + (size_t)(b * NKV + (h >> 2)) * T_SEQ * DH;
    const bf16* Vb = VT + (size_t)(b * NKV + (h >> 2)) * DH * T_SEQ;

    __shared__ __align__(16) union ShmU {
        struct { bf16 SK[2][32 * 128]; bf16 SV[2][128 * 32]; bf16 SP[8][2][16 * 32]; } s;
        ffrag MRG[9 * 4 * 64];               // 36864 B merge area (aliases SK/SV/SP)
    } shm;
    bf16* SKg = shm.s.SK[g];
    bf16* SVg = shm.s.SV[g];

    // staging coords: K chunk 32(keys)x128, V chunk 128(d)x32(keys), per group
    const int k_r0 = wl * 8 + (lane >> 4);   // + j*4
    const int k_ch = lane & 15;
    const int v_r0 = wl * 32 + (lane >> 2);  // + j*16
    const int v_ch = lane & 3;
    const int vsw = (lr + (lr >> 2)) & 3;    // SV read swizzle (row = dt*16+lr)
    const int prow_r = ((lr & 3) << 2) | (lr >> 2);      // P physical row for read
    const int psw = (prow_r + (prow_r >> 2)) & 3;
    const float scale = 0.08838834764831845f;            // 1/sqrt(128)

    for (int pass = 0; pass < 2; ++pass) {
        const int qb = pass ? (15 - p) : p;
        const int nc = 2 * (qb + 1);         // 32-key chunks for THIS group
        const int q0 = qb * 128 + wl * 32;

        bfrag qf[2][4];
        #pragma unroll
        for (int t = 0; t < 2; ++t)
            #pragma unroll
            for (int dc = 0; dc < 4; ++dc)
                qf[t][dc] = *(const bfrag*)(Qb + (size_t)(q0 + t * 16 + lr) * DH + dc * 32 + lk);

        float lp[2][4] = {};
        ffrag o[2][8] = {};

        bfrag kr[2], vr[2];                  // prefetch chunk 0 (abs chunk g)
        {
            const int b0 = g * 32;
            #pragma unroll
            for (int j = 0; j < 2; ++j) {
                kr[j] = *(const bfrag*)(Kb + (size_t)(b0 + k_r0 + j * 4) * DH + k_ch * 8);
                vr[j] = *(const bfrag*)(Vb + (size_t)(v_r0 + j * 16) * T_SEQ + b0 + v_ch * 8);
            }
        }

        for (int c = 0; c < nc; ++c) {
            const int base = c * 64 + g * 32;
            __syncthreads();                 // all waves done reading SK/SV (and MRG)
            #pragma unroll
            for (int j = 0; j < 2; ++j) {
                int krow = k_r0 + j * 4;
                *(bfrag*)&SKg[krow * 128 + ((k_ch ^ (krow & 15))) * 8] = kr[j];
                int vrow = v_r0 + j * 16;
                *(bfrag*)&SVg[vrow * 32 + ((v_ch ^ ((vrow + (vrow >> 2)) & 3))) * 8] = vr[j];
            }
            if (c + 1 < nc) {                // prefetch next; stays in flight across barrier
                const int nb = base + 64;
                #pragma unroll
                for (int j = 0; j < 2; ++j) {
                    kr[j] = *(const bfrag*)(Kb + (size_t)(nb + k_r0 + j * 4) * DH + k_ch * 8);
                    vr[j] = *(const bfrag*)(Vb + (size_t)(v_r0 + j * 16) * T_SEQ + nb + v_ch * 8);
                }
            }
            __syncthreads();                 // staged data visible

            // QK^T: each kf feeds both row-tiles
            ffrag s2[2][2] = {};
            #pragma unroll
            for (int kt = 0; kt < 2; ++kt)
                #pragma unroll
                for (int dc = 0; dc < 4; ++dc) {
                    bfrag kf = *(const bfrag*)&SKg[(kt * 16 + lr) * 128 + (((dc << 2) | quad) ^ lr) * 8];
                    s2[0][kt] = __builtin_amdgcn_mfma_f32_16x16x32_bf16(qf[0][dc], kf, s2[0][kt], 0, 0, 0);
                    s2[1][kt] = __builtin_amdgcn_mfma_f32_16x16x32_bf16(qf[1][dc], kf, s2[1][kt], 0, 0, 0);
                }

            // softmax numerator (static max); P -> LDS, rows 4x4-transposed, chunks swizzled
            const bool maskc = (c >= 2 * qb);
            #pragma unroll
            for (int t = 0; t < 2; ++t)
                #pragma unroll
                for (int kt = 0; kt < 2; ++kt) {
                    const int col = base + kt * 16 + lr;
                    #pragma unroll
                    for (int i = 0; i < 4; ++i) {
                        const int row = q0 + t * 16 + quad * 4 + i;
                        float e = (!maskc || col <= row) ? __expf(fmaf(s2[t][kt][i], scale, -16.0f)) : 0.0f;
                        lp[t][i] += e;
                        const int pr = i * 4 + quad;
                        const int pc = (kt * 2 + (lr >> 3)) ^ ((quad + i) & 3);
                        shm.s.SP[w][t][pr * 32 + pc * 8 + (lr & 7)] = __float2bfloat16(e);
                    }
                }

            // P.V: each vf feeds both row-tiles (per-wave SP: lgkmcnt handles RAW)
            bfrag pf0 = *(const bfrag*)&shm.s.SP[w][0][prow_r * 32 + ((quad ^ psw)) * 8];
            bfrag pf1 = *(const bfrag*)&shm.s.SP[w][1][prow_r * 32 + ((quad ^ psw)) * 8];
            #pragma unroll
            for (int dt = 0; dt < 8; ++dt) {
                bfrag vf = *(const bfrag*)&SVg[(dt * 16 + lr) * 32 + ((quad ^ vsw)) * 8];
                o[0][dt] = __builtin_amdgcn_mfma_f32_16x16x32_bf16(pf0, vf, o[0][dt], 0, 0, 0);
                o[1][dt] = __builtin_amdgcn_mfma_f32_16x16x32_bf16(pf1, vf, o[1][dt], 0, 0, 0);
            }
        }

        // merge groups (fp32, two rounds to fit LDS) + epilogue by group 0
        __syncthreads();
        #pragma unroll
        for (int t = 0; t < 2; ++t) {
            if (g == 1) {
                #pragma unroll
                for (int d = 0; d < 8; ++d) shm.MRG[(d * 4 + wl) * 64 + lane] = o[t][d];
                ffrag l4 = {lp[t][0], lp[t][1], lp[t][2], lp[t][3]};
                shm.MRG[(8 * 4 + wl) * 64 + lane] = l4;
            }
            __syncthreads();
            if (g == 0) {
                #pragma unroll
                for (int d = 0; d < 8; ++d) o[t][d] += shm.MRG[(d * 4 + wl) * 64 + lane];
                ffrag l4 = shm.MRG[(8 * 4 + wl) * 64 + lane];
                float inv[4];
                #pragma unroll
                for (int i = 0; i < 4; ++i) {
                    float l = lp[t][i] + l4[i];
                    #pragma unroll
                    for (int off = 1; off < 16; off <<= 1) l += __shfl_xor(l, off);
                    inv[i] = 1.0f / l;
                }
                #pragma unroll
                for (int dt = 0; dt < 8; ++dt)
                    #pragma unroll
                    for (int i = 0; i < 4; ++i) {
                        int row = q0 + t * 16 + quad * 4 + i;
                        Y[((size_t)(b * T_SEQ) + row) * CDIM + h * DH + dt * 16 + lr] =
                            __float2bfloat16(o[t][dt][i] * inv[i]);
                    }
            }
            __syncthreads();                 // protect MRG before next round / next pass
        }
    }
}

extern "C" void kernel_launch(void* const* d_in, const int* in_sizes, int n_in,
                              void* d_out, int out_size, void* d_ws, size_t ws_size,
                              hipStream_t stream) {
    const float* x     = (const float*)d_in[0];
    const float* Wq    = (const float*)d_in[1];
    const float* Wkv   = (const float*)d_in[2];
    const float* Wproj = (const float*)d_in[3];
    float* out = (float*)d_out;

    char* ws = (char*)d_ws;
    size_t off = 0;
    auto alloc = [&](size_t bytes) { void* p = ws + off; off += (bytes + 255) & ~255ULL; return p; };
    bf16* xb   = (bf16*)alloc((size_t)BATCH * T_SEQ * CDIM * 2);
    bf16* wqb  = (bf16*)alloc((size_t)CDIM * CDIM * 2);
    bf16* wkvb = (bf16*)alloc((size_t)2 * NKV * DH * CDIM * 2);
    bf16* wpb  = (bf16*)alloc((size_t)CDIM * CDIM * 2);
    bf16* qb   = (bf16*)alloc((size_t)BATCH * NH * T_SEQ * DH * 2);
    bf16* kb   = (bf16*)alloc((size_t)BATCH * NKV * T_SEQ * DH * 2);
    bf16* vtb  = (bf16*)alloc((size_t)BATCH * NKV * DH * T_SEQ * 2);
    bf16* y1   = (bf16*)alloc((size_t)BATCH * T_SEQ * CDIM * 2);

    const int total4 = N4_X + N4_WQ + N4_WKV + N4_WP;
    cast_all<<<(total4 + 255) / 256, 256, 0, stream>>>(x, Wq, Wkv, Wproj, xb, wqb, wkvb, wpb);

    gemm_qkv<<<dim3(192), 512, 0, stream>>>(xb, wqb, wkvb, qb, kb, vtb);
    normrope_k<<<(QROWS + KROWS) / 4, 256, 0, stream>>>(qb, kb);
    attn_k<<<dim3(8, NH, BATCH), 512, 0, stream>>>(qb, kb, vtb, y1);
    gemm_proj<<<dim3(256), 512, 0, stream>>>(y1, wpb, out);
}

// Round 3
// 299.212 us; speedup vs baseline: 1.0216x; 1.0134x over previous
//
#include <hip/hip_runtime.h>
#include <hip/hip_bf16.h>

#define T_SEQ 2048
#define BATCH 2
#define CDIM  2048
#define NH    16
#define NKV   4
#define DH    128

typedef __attribute__((ext_vector_type(8))) short bfrag;   // 8 bf16 (4 VGPRs)
typedef __attribute__((ext_vector_type(4))) float ffrag;   // 4 f32 acc
typedef __hip_bfloat16 bf16;

__device__ __forceinline__ void gll16(const bf16* __restrict__ g, bf16* lds) {
    __builtin_amdgcn_global_load_lds((const __attribute__((address_space(1))) void*)g,
                                     (__attribute__((address_space(3))) void*)lds, 16, 0, 0);
}

// ---------------- merged fp32 -> bf16 cast of all 4 inputs ----------------
struct bf16x4 { bf16 a, b, c, d; };
#define N4_X   (BATCH * T_SEQ * CDIM / 4)
#define N4_WQ  (CDIM * CDIM / 4)
#define N4_WKV (2 * NKV * DH * CDIM / 4)
#define N4_WP  (CDIM * CDIM / 4)
__global__ __launch_bounds__(256) void cast_all(
    const float* __restrict__ x, const float* __restrict__ wq,
    const float* __restrict__ wkv, const float* __restrict__ wp,
    bf16* __restrict__ xb, bf16* __restrict__ wqb, bf16* __restrict__ wkvb, bf16* __restrict__ wpb)
{
    int j = blockIdx.x * 256 + threadIdx.x;
    const float* s; bf16* d;
    if (j < N4_X) { s = x; d = xb; }
    else {
        j -= N4_X;
        if (j < N4_WQ) { s = wq; d = wqb; }
        else {
            j -= N4_WQ;
            if (j < N4_WKV) { s = wkv; d = wkvb; }
            else { j -= N4_WKV; if (j >= N4_WP) return; s = wp; d = wpb; }
        }
    }
    float4 f = ((const float4*)s)[j];
    bf16x4 o{__float2bfloat16(f.x), __float2bfloat16(f.y),
             __float2bfloat16(f.z), __float2bfloat16(f.w)};
    ((bf16x4*)d)[j] = o;
}

// ---------------- GEMM: round-0 (m97/TLP) structure + zero-conflict LDS geometry ----------------
// 128x128 tile, 4 waves (2M x 2N), BK=32, single LDS buffer, 2 __syncthreads per tile,
// multi-block TLP (16 KiB LDS, ~4 blocks/CU) hides the vmcnt(0) barrier drain.
// LDS geometry (the only change vs round 0): logical [128 rows][32 k] packed as
// phys [64 rows][64 elems] (row pair -> one 128 B phys row = 8 x 16 B slots);
// slot ^= (prow & 7), applied to the global SOURCE address for staging (since
// global_load_lds writes linearly: base + lane*16) and to the ds_read address.
// This exact geometry measured SQ_LDS_BANK_CONFLICT == 0 in rounds 1-2.
template<int MODE>
__device__ __forceinline__ void gemm_body(
    const bf16* __restrict__ A, const bf16* __restrict__ W, int m0, int n0,
    bf16* __restrict__ out0, bf16* __restrict__ out1, float* __restrict__ outf)
{
    __shared__ __align__(16) bf16 sA[64 * 64];   // 8 KiB
    __shared__ __align__(16) bf16 sB[64 * 64];   // 8 KiB

    const int lane = threadIdx.x & 63;
    const int w    = threadIdx.x >> 6;           // 0..3
    const int wm   = w >> 1, wn = w & 1;
    const int lr   = lane & 15, quad = lane >> 4;

    // staging: wave w + block-load j covers phys rows j*32 + w*8 + (lane>>3)
    const int pr8  = lane >> 3;                  // phys row-in-8
    const int ls   = (lane & 7) ^ pr8;           // logical slot after inverse swizzle
    const int rloc = 2 * (w * 8 + pr8) + (ls >> 2);  // logical row within 64-row block-load
    const int k0s  = (ls & 3) * 8;               // k sub-offset 0..24

    const bf16* Aj0 = A + (size_t)(m0 +      rloc) * CDIM + k0s;
    const bf16* Aj1 = A + (size_t)(m0 + 64 + rloc) * CDIM + k0s;
    const bf16* Bj0 = W + (size_t)(n0 +      rloc) * CDIM + k0s;
    const bf16* Bj1 = W + (size_t)(n0 + 64 + rloc) * CDIM + k0s;
    bf16* dA0 = sA +        w * 512;             // wave-uniform LDS dest (elems)
    bf16* dA1 = sA + 2048 + w * 512;
    bf16* dB0 = sB +        w * 512;
    bf16* dB1 = sB + 2048 + w * 512;

    // fragment-read swizzled slot offset (elems); XOR key = prow&7 = (lr>>1)&7
    const int soff = ((((lr & 1) << 2) | quad) ^ ((lr >> 1) & 7)) << 3;

    ffrag acc[4][4] = {};
    for (int kk = 0; kk < CDIM; kk += 32) {
        __syncthreads();                         // all waves done reading previous tile
        gll16(Aj0 + kk, dA0);
        gll16(Aj1 + kk, dA1);
        gll16(Bj0 + kk, dB0);
        gll16(Bj1 + kk, dB1);
        __syncthreads();                         // vmcnt(0) drain + barrier: staged data visible

        bfrag af[4], bg[4];
        #pragma unroll
        for (int f = 0; f < 4; ++f)
            af[f] = *(const bfrag*)&sA[((f * 16 + wm * 8 + (lr >> 1)) << 6) + soff];
        #pragma unroll
        for (int g = 0; g < 4; ++g)
            bg[g] = *(const bfrag*)&sB[((g * 16 + wn * 8 + (lr >> 1)) << 6) + soff];
        #pragma unroll
        for (int f = 0; f < 4; ++f)
            #pragma unroll
            for (int g = 0; g < 4; ++g)
                acc[f][g] = __builtin_amdgcn_mfma_f32_16x16x32_bf16(af[f], bg[g], acc[f][g], 0, 0, 0);
    }

    #pragma unroll
    for (int f = 0; f < 4; ++f) {
        #pragma unroll
        for (int g = 0; g < 4; ++g) {
            #pragma unroll
            for (int i = 0; i < 4; ++i) {
                const int m = m0 + f * 32 + wm * 16 + quad * 4 + i;
                const int n = n0 + g * 32 + wn * 16 + lr;
                const float v = acc[f][g][i];
                if constexpr (MODE == 0) {
                    int b = m >> 11, t = m & (T_SEQ - 1);
                    int h = n >> 7, d = n & (DH - 1);
                    out0[(((size_t)(b * NH + h) * T_SEQ + t) << 7) + d] = __float2bfloat16(v);
                } else if constexpr (MODE == 1) {
                    int b = m >> 11, t = m & (T_SEQ - 1);
                    if (n < NKV * DH) {
                        int h = n >> 7, d = n & (DH - 1);
                        out0[(((size_t)(b * NKV + h) * T_SEQ + t) << 7) + d] = __float2bfloat16(v);
                    } else {
                        int n2 = n - NKV * DH;
                        int h = n2 >> 7, d = n2 & (DH - 1);
                        out1[(((size_t)(b * NKV + h) * DH + d) << 11) + t] = __float2bfloat16(v);
                    }
                } else {
                    outf[(size_t)m * CDIM + n] = v;
                }
            }
        }
    }
}

__global__ __launch_bounds__(256) void gemm_qkv(
    const bf16* __restrict__ A, const bf16* __restrict__ Wq, const bf16* __restrict__ Wkv,
    bf16* __restrict__ q, bf16* __restrict__ k, bf16* __restrict__ vt)
{
    if (blockIdx.y < 16)
        gemm_body<0>(A, Wq, blockIdx.x * 128, blockIdx.y * 128, q, nullptr, nullptr);
    else
        gemm_body<1>(A, Wkv, blockIdx.x * 128, (blockIdx.y - 16) * 128, k, vt, nullptr);
}

__global__ __launch_bounds__(256) void gemm_proj(
    const bf16* __restrict__ A, const bf16* __restrict__ W, float* __restrict__ outf)
{
    gemm_body<2>(A, W, blockIdx.x * 128, blockIdx.y * 128, nullptr, nullptr, outf);
    if (blockIdx.x == 0 && blockIdx.y == 0 && threadIdx.x == 0)
        outf[(size_t)BATCH * T_SEQ * CDIM] = 0.0f;   // reference's second output: 0.0
}

// ---------------- RMSNorm + rotary, q and k fused in one launch ----------------
#define QROWS (BATCH * NH * T_SEQ)
#define KROWS (BATCH * NKV * T_SEQ)
__global__ __launch_bounds__(256) void normrope_k(bf16* __restrict__ qb, bf16* __restrict__ kb) {
    int row = blockIdx.x * 4 + (threadIdx.x >> 6);
    bf16* bufb; int nheads;
    if (row < QROWS) { bufb = qb; nheads = NH; }
    else { row -= QROWS; bufb = kb; nheads = NKV; }
    const int h = (row >> 11) % nheads;            // T = 2^11; angle uses HEAD idx (per ref)
    bf16* p = bufb + (size_t)row * DH;
    const int d = threadIdx.x & 63;
    float x1 = __bfloat162float(p[d]);
    float x2 = __bfloat162float(p[d + 64]);
    float ss = x1 * x1 + x2 * x2;
    #pragma unroll
    for (int off = 32; off; off >>= 1) ss += __shfl_xor(ss, off);
    float r = rsqrtf(ss * (1.0f / 128.0f) + 1.1920929e-07f);
    x1 *= r; x2 *= r;
    float freq = (d < 32) ? exp2f(-10.0f * (float)d * (1.0f / 31.0f)) : 0.0f;
    float th = (float)h * freq;
    float c, s;
    __sincosf(th, &s, &c);
    p[d]      = __float2bfloat16(x1 * c + x2 * s);
    p[d + 64] = __float2bfloat16(-x1 * s + x2 * c);
}

// ---------------- Flash attention v5: 8 waves, even/odd chunk groups ----------------
// Static-max softmax (RMS-normed q,k => |score*scale| <= 11.32; exp(s-16) exact).
// Block = 512 thr: group g = waves 0-3 / 4-7; both groups cover the same 128 q-rows
// (wave wl -> rows qb*128 + wl*32, two 16-row tiles) but disjoint 32-key chunks
// (abs chunk 2c+g). Partial (O, l) add linearly (static max) -> fp32 LDS merge.
// Pass pairing (p, 15-p) => uniform 34 group-chunks/block. All LDS arrays are
// unpadded with XOR-chunk swizzle => every access <=2-way (free).
__global__ __launch_bounds__(512, 2) void attn_k(const bf16* __restrict__ Q, const bf16* __restrict__ K,
                                                 const bf16* __restrict__ VT, bf16* __restrict__ Y)
{
    const int lane = threadIdx.x & 63;
    const int w = threadIdx.x >> 6;          // 0..7
    const int g = w >> 2, wl = w & 3;
    const int p = blockIdx.x, h = blockIdx.y, b = blockIdx.z;
    const int lr = lane & 15, quad = lane >> 4, lk = quad * 8;
    const bf16* Qb = Q  + (size_t)(b * NH  + h)        * T_SEQ * DH;
    const bf16* Kb = K  + (size_t)(b * NKV + (h >> 2)) * T_SEQ * DH;
    const bf16* Vb = VT + (size_t)(b * NKV + (h >> 2)) * DH * T_SEQ;

    __shared__ __align__(16) union ShmU {
        struct { bf16 SK[2][32 * 128]; bf16 SV[2][128 * 32]; bf16 SP[8][2][16 * 32]; } s;
        ffrag MRG[9 * 4 * 64];               // 36864 B merge area (aliases SK/SV/SP)
    } shm;
    bf16* SKg = shm.s.SK[g];
    bf16* SVg = shm.s.SV[g];

    // staging coords: K chunk 32(keys)x128, V chunk 128(d)x32(keys), per group
    const int k_r0 = wl * 8 + (lane >> 4);   // + j*4
    const int k_ch = lane & 15;
    const int v_r0 = wl * 32 + (lane >> 2);  // + j*16
    const int v_ch = lane & 3;
    const int vsw = (lr + (lr >> 2)) & 3;    // SV read swizzle (row = dt*16+lr)
    const int prow_r = ((lr & 3) << 2) | (lr >> 2);      // P physical row for read
    const int psw = (prow_r + (prow_r >> 2)) & 3;
    const float scale = 0.08838834764831845f;            // 1/sqrt(128)

    for (int pass = 0; pass < 2; ++pass) {
        const int qb = pass ? (15 - p) : p;
        const int nc = 2 * (qb + 1);         // 32-key chunks for THIS group
        const int q0 = qb * 128 + wl * 32;

        bfrag qf[2][4];
        #pragma unroll
        for (int t = 0; t < 2; ++t)
            #pragma unroll
            for (int dc = 0; dc < 4; ++dc)
                qf[t][dc] = *(const bfrag*)(Qb + (size_t)(q0 + t * 16 + lr) * DH + dc * 32 + lk);

        float lp[2][4] = {};
        ffrag o[2][8] = {};

        bfrag kr[2], vr[2];                  // prefetch chunk 0 (abs chunk g)
        {
            const int b0 = g * 32;
            #pragma unroll
            for (int j = 0; j < 2; ++j) {
                kr[j] = *(const bfrag*)(Kb + (size_t)(b0 + k_r0 + j * 4) * DH + k_ch * 8);
                vr[j] = *(const bfrag*)(Vb + (size_t)(v_r0 + j * 16) * T_SEQ + b0 + v_ch * 8);
            }
        }

        for (int c = 0; c < nc; ++c) {
            const int base = c * 64 + g * 32;
            __syncthreads();                 // all waves done reading SK/SV (and MRG)
            #pragma unroll
            for (int j = 0; j < 2; ++j) {
                int krow = k_r0 + j * 4;
                *(bfrag*)&SKg[krow * 128 + ((k_ch ^ (krow & 15))) * 8] = kr[j];
                int vrow = v_r0 + j * 16;
                *(bfrag*)&SVg[vrow * 32 + ((v_ch ^ ((vrow + (vrow >> 2)) & 3))) * 8] = vr[j];
            }
            if (c + 1 < nc) {                // prefetch next; stays in flight across barrier
                const int nb = base + 64;
                #pragma unroll
                for (int j = 0; j < 2; ++j) {
                    kr[j] = *(const bfrag*)(Kb + (size_t)(nb + k_r0 + j * 4) * DH + k_ch * 8);
                    vr[j] = *(const bfrag*)(Vb + (size_t)(v_r0 + j * 16) * T_SEQ + nb + v_ch * 8);
                }
            }
            __syncthreads();                 // staged data visible

            // QK^T: each kf feeds both row-tiles
            ffrag s2[2][2] = {};
            #pragma unroll
            for (int kt = 0; kt < 2; ++kt)
                #pragma unroll
                for (int dc = 0; dc < 4; ++dc) {
                    bfrag kf = *(const bfrag*)&SKg[(kt * 16 + lr) * 128 + (((dc << 2) | quad) ^ lr) * 8];
                    s2[0][kt] = __builtin_amdgcn_mfma_f32_16x16x32_bf16(qf[0][dc], kf, s2[0][kt], 0, 0, 0);
                    s2[1][kt] = __builtin_amdgcn_mfma_f32_16x16x32_bf16(qf[1][dc], kf, s2[1][kt], 0, 0, 0);
                }

            // softmax numerator (static max); P -> LDS, rows 4x4-transposed, chunks swizzled
            const bool maskc = (c >= 2 * qb);
            #pragma unroll
            for (int t = 0; t < 2; ++t)
                #pragma unroll
                for (int kt = 0; kt < 2; ++kt) {
                    const int col = base + kt * 16 + lr;
                    #pragma unroll
                    for (int i = 0; i < 4; ++i) {
                        const int row = q0 + t * 16 + quad * 4 + i;
                        float e = (!maskc || col <= row) ? __expf(fmaf(s2[t][kt][i], scale, -16.0f)) : 0.0f;
                        lp[t][i] += e;
                        const int pr = i * 4 + quad;
                        const int pc = (kt * 2 + (lr >> 3)) ^ ((quad + i) & 3);
                        shm.s.SP[w][t][pr * 32 + pc * 8 + (lr & 7)] = __float2bfloat16(e);
                    }
                }

            // P.V: each vf feeds both row-tiles (per-wave SP: lgkmcnt handles RAW)
            bfrag pf0 = *(const bfrag*)&shm.s.SP[w][0][prow_r * 32 + ((quad ^ psw)) * 8];
            bfrag pf1 = *(const bfrag*)&shm.s.SP[w][1][prow_r * 32 + ((quad ^ psw)) * 8];
            #pragma unroll
            for (int dt = 0; dt < 8; ++dt) {
                bfrag vf = *(const bfrag*)&SVg[(dt * 16 + lr) * 32 + ((quad ^ vsw)) * 8];
                o[0][dt] = __builtin_amdgcn_mfma_f32_16x16x32_bf16(pf0, vf, o[0][dt], 0, 0, 0);
                o[1][dt] = __builtin_amdgcn_mfma_f32_16x16x32_bf16(pf1, vf, o[1][dt], 0, 0, 0);
            }
        }

        // merge groups (fp32, two rounds to fit LDS) + epilogue by group 0
        __syncthreads();
        #pragma unroll
        for (int t = 0; t < 2; ++t) {
            if (g == 1) {
                #pragma unroll
                for (int d = 0; d < 8; ++d) shm.MRG[(d * 4 + wl) * 64 + lane] = o[t][d];
                ffrag l4 = {lp[t][0], lp[t][1], lp[t][2], lp[t][3]};
                shm.MRG[(8 * 4 + wl) * 64 + lane] = l4;
            }
            __syncthreads();
            if (g == 0) {
                #pragma unroll
                for (int d = 0; d < 8; ++d) o[t][d] += shm.MRG[(d * 4 + wl) * 64 + lane];
                ffrag l4 = shm.MRG[(8 * 4 + wl) * 64 + lane];
                float inv[4];
                #pragma unroll
                for (int i = 0; i < 4; ++i) {
                    float l = lp[t][i] + l4[i];
                    #pragma unroll
                    for (int off = 1; off < 16; off <<= 1) l += __shfl_xor(l, off);
                    inv[i] = 1.0f / l;
                }
                #pragma unroll
                for (int dt = 0; dt < 8; ++dt)
                    #pragma unroll
                    for (int i = 0; i < 4; ++i) {
                        int row = q0 + t * 16 + quad * 4 + i;
                        Y[((size_t)(b * T_SEQ) + row) * CDIM + h * DH + dt * 16 + lr] =
                            __float2bfloat16(o[t][dt][i] * inv[i]);
                    }
            }
            __syncthreads();                 // protect MRG before next round / next pass
        }
    }
}

extern "C" void kernel_launch(void* const* d_in, const int* in_sizes, int n_in,
                              void* d_out, int out_size, void* d_ws, size_t ws_size,
                              hipStream_t stream) {
    const float* x     = (const float*)d_in[0];
    const float* Wq    = (const float*)d_in[1];
    const float* Wkv   = (const float*)d_in[2];
    const float* Wproj = (const float*)d_in[3];
    float* out = (float*)d_out;

    char* ws = (char*)d_ws;
    size_t off = 0;
    auto alloc = [&](size_t bytes) { void* p = ws + off; off += (bytes + 255) & ~255ULL; return p; };
    bf16* xb   = (bf16*)alloc((size_t)BATCH * T_SEQ * CDIM * 2);
    bf16* wqb  = (bf16*)alloc((size_t)CDIM * CDIM * 2);
    bf16* wkvb = (bf16*)alloc((size_t)2 * NKV * DH * CDIM * 2);
    bf16* wpb  = (bf16*)alloc((size_t)CDIM * CDIM * 2);
    bf16* qb   = (bf16*)alloc((size_t)BATCH * NH * T_SEQ * DH * 2);
    bf16* kb   = (bf16*)alloc((size_t)BATCH * NKV * T_SEQ * DH * 2);
    bf16* vtb  = (bf16*)alloc((size_t)BATCH * NKV * DH * T_SEQ * 2);
    bf16* y1   = (bf16*)alloc((size_t)BATCH * T_SEQ * CDIM * 2);

    const int total4 = N4_X + N4_WQ + N4_WKV + N4_WP;
    cast_all<<<(total4 + 255) / 256, 256, 0, stream>>>(x, Wq, Wkv, Wproj, xb, wqb, wkvb, wpb);

    gemm_qkv<<<dim3(32, 24), 256, 0, stream>>>(xb, wqb, wkvb, qb, kb, vtb);
    normrope_k<<<(QROWS + KROWS) / 4, 256, 0, stream>>>(qb, kb);
    attn_k<<<dim3(8, NH, BATCH), 512, 0, stream>>>(qb, kb, vtb, y1);
    gemm_proj<<<dim3(32, 16), 256, 0, stream>>>(y1, wpb, out);
}

// Round 4
// 298.443 us; speedup vs baseline: 1.0242x; 1.0026x over previous
//
#include <hip/hip_runtime.h>
#include <hip/hip_bf16.h>

#define T_SEQ 2048
#define BATCH 2
#define CDIM  2048
#define NH    16
#define NKV   4
#define DH    128

typedef __attribute__((ext_vector_type(8))) short bfrag;   // 8 bf16 (4 VGPRs)
typedef __attribute__((ext_vector_type(4))) short bhalf;   // 4 bf16 (2 VGPRs)
typedef __attribute__((ext_vector_type(4))) float ffrag;   // 4 f32 acc
typedef __hip_bfloat16 bf16;

__device__ __forceinline__ void gll16(const bf16* __restrict__ g, bf16* lds) {
    __builtin_amdgcn_global_load_lds((const __attribute__((address_space(1))) void*)g,
                                     (__attribute__((address_space(3))) void*)lds, 16, 0, 0);
}

__device__ __forceinline__ unsigned cvt_pk_bf16(float lo, float hi) {
    unsigned r;
    asm("v_cvt_pk_bf16_f32 %0, %1, %2" : "=v"(r) : "v"(lo), "v"(hi));
    return r;   // low16 = bf16(lo), high16 = bf16(hi)
}

// ---------------- merged fp32 -> bf16 cast of all 4 inputs ----------------
struct bf16x4 { bf16 a, b, c, d; };
#define N4_X   (BATCH * T_SEQ * CDIM / 4)
#define N4_WQ  (CDIM * CDIM / 4)
#define N4_WKV (2 * NKV * DH * CDIM / 4)
#define N4_WP  (CDIM * CDIM / 4)
__global__ __launch_bounds__(256) void cast_all(
    const float* __restrict__ x, const float* __restrict__ wq,
    const float* __restrict__ wkv, const float* __restrict__ wp,
    bf16* __restrict__ xb, bf16* __restrict__ wqb, bf16* __restrict__ wkvb, bf16* __restrict__ wpb)
{
    int j = blockIdx.x * 256 + threadIdx.x;
    const float* s; bf16* d;
    if (j < N4_X) { s = x; d = xb; }
    else {
        j -= N4_X;
        if (j < N4_WQ) { s = wq; d = wqb; }
        else {
            j -= N4_WQ;
            if (j < N4_WKV) { s = wkv; d = wkvb; }
            else { j -= N4_WKV; if (j >= N4_WP) return; s = wp; d = wpb; }
        }
    }
    float4 f = ((const float4*)s)[j];
    bf16x4 o{__float2bfloat16(f.x), __float2bfloat16(f.y),
             __float2bfloat16(f.z), __float2bfloat16(f.w)};
    ((bf16x4*)d)[j] = o;
}

// ---------------- GEMM: m97/TLP structure + zero-conflict LDS geometry ----------------
// 128x128 tile, 4 waves (2M x 2N), BK=32, single LDS buffer, 2 __syncthreads per tile,
// multi-block TLP hides the barrier drain. LDS: logical [128 rows][32 k] packed as
// phys [64 rows][64 elems]; 16B slot ^= (prow & 7), applied to the global SOURCE for
// staging (global_load_lds writes linearly) and to the ds_read address.
// Measured SQ_LDS_BANK_CONFLICT == 0 with this geometry.
template<int MODE>
__device__ __forceinline__ void gemm_body(
    const bf16* __restrict__ A, const bf16* __restrict__ W, int m0, int n0,
    bf16* __restrict__ out0, bf16* __restrict__ out1, float* __restrict__ outf)
{
    __shared__ __align__(16) bf16 sA[64 * 64];   // 8 KiB
    __shared__ __align__(16) bf16 sB[64 * 64];   // 8 KiB

    const int lane = threadIdx.x & 63;
    const int w    = threadIdx.x >> 6;           // 0..3
    const int wm   = w >> 1, wn = w & 1;
    const int lr   = lane & 15, quad = lane >> 4;

    const int pr8  = lane >> 3;                  // phys row-in-8
    const int ls   = (lane & 7) ^ pr8;           // logical slot after inverse swizzle
    const int rloc = 2 * (w * 8 + pr8) + (ls >> 2);  // logical row within 64-row block-load
    const int k0s  = (ls & 3) * 8;               // k sub-offset 0..24

    const bf16* Aj0 = A + (size_t)(m0 +      rloc) * CDIM + k0s;
    const bf16* Aj1 = A + (size_t)(m0 + 64 + rloc) * CDIM + k0s;
    const bf16* Bj0 = W + (size_t)(n0 +      rloc) * CDIM + k0s;
    const bf16* Bj1 = W + (size_t)(n0 + 64 + rloc) * CDIM + k0s;
    bf16* dA0 = sA +        w * 512;             // wave-uniform LDS dest (elems)
    bf16* dA1 = sA + 2048 + w * 512;
    bf16* dB0 = sB +        w * 512;
    bf16* dB1 = sB + 2048 + w * 512;

    const int soff = ((((lr & 1) << 2) | quad) ^ ((lr >> 1) & 7)) << 3;

    ffrag acc[4][4] = {};
    for (int kk = 0; kk < CDIM; kk += 32) {
        __syncthreads();                         // all waves done reading previous tile
        gll16(Aj0 + kk, dA0);
        gll16(Aj1 + kk, dA1);
        gll16(Bj0 + kk, dB0);
        gll16(Bj1 + kk, dB1);
        __syncthreads();                         // vmcnt(0) drain + barrier: staged data visible

        bfrag af[4], bg[4];
        #pragma unroll
        for (int f = 0; f < 4; ++f)
            af[f] = *(const bfrag*)&sA[((f * 16 + wm * 8 + (lr >> 1)) << 6) + soff];
        #pragma unroll
        for (int g = 0; g < 4; ++g)
            bg[g] = *(const bfrag*)&sB[((g * 16 + wn * 8 + (lr >> 1)) << 6) + soff];
        #pragma unroll
        for (int f = 0; f < 4; ++f)
            #pragma unroll
            for (int g = 0; g < 4; ++g)
                acc[f][g] = __builtin_amdgcn_mfma_f32_16x16x32_bf16(af[f], bg[g], acc[f][g], 0, 0, 0);
    }

    #pragma unroll
    for (int f = 0; f < 4; ++f) {
        #pragma unroll
        for (int g = 0; g < 4; ++g) {
            #pragma unroll
            for (int i = 0; i < 4; ++i) {
                const int m = m0 + f * 32 + wm * 16 + quad * 4 + i;
                const int n = n0 + g * 32 + wn * 16 + lr;
                const float v = acc[f][g][i];
                if constexpr (MODE == 0) {
                    int b = m >> 11, t = m & (T_SEQ - 1);
                    int h = n >> 7, d = n & (DH - 1);
                    out0[(((size_t)(b * NH + h) * T_SEQ + t) << 7) + d] = __float2bfloat16(v);
                } else if constexpr (MODE == 1) {
                    int b = m >> 11, t = m & (T_SEQ - 1);
                    if (n < NKV * DH) {
                        int h = n >> 7, d = n & (DH - 1);
                        out0[(((size_t)(b * NKV + h) * T_SEQ + t) << 7) + d] = __float2bfloat16(v);
                    } else {
                        int n2 = n - NKV * DH;
                        int h = n2 >> 7, d = n2 & (DH - 1);
                        out1[(((size_t)(b * NKV + h) * DH + d) << 11) + t] = __float2bfloat16(v);
                    }
                } else {
                    outf[(size_t)m * CDIM + n] = v;
                }
            }
        }
    }
}

__global__ __launch_bounds__(256) void gemm_qkv(
    const bf16* __restrict__ A, const bf16* __restrict__ Wq, const bf16* __restrict__ Wkv,
    bf16* __restrict__ q, bf16* __restrict__ k, bf16* __restrict__ vt)
{
    if (blockIdx.y < 16)
        gemm_body<0>(A, Wq, blockIdx.x * 128, blockIdx.y * 128, q, nullptr, nullptr);
    else
        gemm_body<1>(A, Wkv, blockIdx.x * 128, (blockIdx.y - 16) * 128, k, vt, nullptr);
}

__global__ __launch_bounds__(256) void gemm_proj(
    const bf16* __restrict__ A, const bf16* __restrict__ W, float* __restrict__ outf)
{
    gemm_body<2>(A, W, blockIdx.x * 128, blockIdx.y * 128, nullptr, nullptr, outf);
    if (blockIdx.x == 0 && blockIdx.y == 0 && threadIdx.x == 0)
        outf[(size_t)BATCH * T_SEQ * CDIM] = 0.0f;   // reference's second output: 0.0
}

// ---------------- RMSNorm + rotary, q and k fused in one launch ----------------
#define QROWS (BATCH * NH * T_SEQ)
#define KROWS (BATCH * NKV * T_SEQ)
__global__ __launch_bounds__(256) void normrope_k(bf16* __restrict__ qb, bf16* __restrict__ kb) {
    int row = blockIdx.x * 4 + (threadIdx.x >> 6);
    bf16* bufb; int nheads;
    if (row < QROWS) { bufb = qb; nheads = NH; }
    else { row -= QROWS; bufb = kb; nheads = NKV; }
    const int h = (row >> 11) % nheads;            // T = 2^11; angle uses HEAD idx (per ref)
    bf16* p = bufb + (size_t)row * DH;
    const int d = threadIdx.x & 63;
    float x1 = __bfloat162float(p[d]);
    float x2 = __bfloat162float(p[d + 64]);
    float ss = x1 * x1 + x2 * x2;
    #pragma unroll
    for (int off = 32; off; off >>= 1) ss += __shfl_xor(ss, off);
    float r = rsqrtf(ss * (1.0f / 128.0f) + 1.1920929e-07f);
    x1 *= r; x2 *= r;
    float freq = (d < 32) ? exp2f(-10.0f * (float)d * (1.0f / 31.0f)) : 0.0f;
    float th = (float)h * freq;
    float c, s;
    __sincosf(th, &s, &c);
    p[d]      = __float2bfloat16(x1 * c + x2 * s);
    p[d + 64] = __float2bfloat16(-x1 * s + x2 * c);
}

// ---------------- Flash attention v6: swapped QK^T, in-register P ----------------
// Static-max softmax (RMS-normed q,k => |score*scale| <= 11.32; exp(s-16) exact).
// Block = 512 thr: group g = waves 0-3 / 4-7; both groups cover the same 128 q-rows
// (wave wl -> rows qb*128 + wl*32, two 16-row tiles) but disjoint 32-key chunks
// (abs chunk 2c+g). Partial (O, l) add linearly (static max) -> fp32 LDS merge.
// Pass pairing (p, 15-p) => uniform 34 group-chunks/block.
//
// v6 change: QK^T computed SWAPPED: s2 = mfma(kf, qf) (A/B fragments have identical
// lane layouts, so the same register data works for either operand). Output layout:
// lane (quad,lr) holds S[k = kt*16 + quad*4 + i][q = lr] -- every lane's scores are
// for its OWN q = lr. The PV A-fragment (P[q=lr][k-slice(quad)]) is then built fully
// in-register with 8 v_cvt_pk_bf16_f32 per chunk: NO LDS round-trip for P (removes
// 16 ds_write_b16 + 2 ds_read_b128 + 16 scalar converts per chunk-wave, and the
// softmax->PV lgkmcnt serialization). Requirement: V's k-order inside each 16B LDS
// slot must match pf's word order: slot s holds k = {4s..4s+3, 16+4s..16+4s+3}
// (achieved by splitting each V staging load into two 8B global loads; LDS write/read
// addresses and swizzle unchanged). l-sum is now per-lane over the quad k-slice;
// final reduce is shfl_xor over quads (16,32) + 4 shfl redistributes.
__global__ __launch_bounds__(512, 2) void attn_k(const bf16* __restrict__ Q, const bf16* __restrict__ K,
                                                 const bf16* __restrict__ VT, bf16* __restrict__ Y)
{
    const int lane = threadIdx.x & 63;
    const int w = threadIdx.x >> 6;          // 0..7
    const int g = w >> 2, wl = w & 3;
    const int p = blockIdx.x, h = blockIdx.y, b = blockIdx.z;
    const int lr = lane & 15, quad = lane >> 4, lk = quad * 8;
    const bf16* Qb = Q  + (size_t)(b * NH  + h)        * T_SEQ * DH;
    const bf16* Kb = K  + (size_t)(b * NKV + (h >> 2)) * T_SEQ * DH;
    const bf16* Vb = VT + (size_t)(b * NKV + (h >> 2)) * DH * T_SEQ;

    __shared__ __align__(16) union ShmU {
        struct { bf16 SK[2][32 * 128]; bf16 SV[2][128 * 32]; } s;   // 32 KiB
        ffrag MRG[9 * 4 * 64];               // 36864 B merge area (aliases SK/SV)
    } shm;
    bf16* SKg = shm.s.SK[g];
    bf16* SVg = shm.s.SV[g];

    // staging coords: K chunk 32(keys)x128, V chunk 128(d)x32(keys), per group
    const int k_r0 = wl * 8 + (lane >> 4);   // + j*4
    const int k_ch = lane & 15;
    const int v_r0 = wl * 32 + (lane >> 2);  // + j*16
    const int v_ch = lane & 3;
    const int vsw = (lr + (lr >> 2)) & 3;    // SV read swizzle (row = dt*16+lr)
    const float scale = 0.08838834764831845f;            // 1/sqrt(128)

    // k-permuted V load: slot v_ch holds k = {4*v_ch..+3, 16+4*v_ch..+3}
    auto load_v_perm = [&](const bf16* rp) {
        union { bhalf h[2]; bfrag f; } u;
        u.h[0] = *(const bhalf*)(rp + v_ch * 4);
        u.h[1] = *(const bhalf*)(rp + 16 + v_ch * 4);
        return u.f;
    };

    for (int pass = 0; pass < 2; ++pass) {
        const int qb = pass ? (15 - p) : p;
        const int nc = 2 * (qb + 1);         // 32-key chunks for THIS group
        const int q0 = qb * 128 + wl * 32;

        bfrag qf[2][4];
        #pragma unroll
        for (int t = 0; t < 2; ++t)
            #pragma unroll
            for (int dc = 0; dc < 4; ++dc)
                qf[t][dc] = *(const bfrag*)(Qb + (size_t)(q0 + t * 16 + lr) * DH + dc * 32 + lk);

        float lp[2] = {};
        ffrag o[2][8] = {};

        bfrag kr[2], vr[2];                  // prefetch chunk 0 (abs chunk g)
        {
            const int b0 = g * 32;
            #pragma unroll
            for (int j = 0; j < 2; ++j) {
                kr[j] = *(const bfrag*)(Kb + (size_t)(b0 + k_r0 + j * 4) * DH + k_ch * 8);
                vr[j] = load_v_perm(Vb + (size_t)(v_r0 + j * 16) * T_SEQ + b0);
            }
        }

        for (int c = 0; c < nc; ++c) {
            const int base = c * 64 + g * 32;
            __syncthreads();                 // all waves done reading SK/SV (and MRG)
            #pragma unroll
            for (int j = 0; j < 2; ++j) {
                int krow = k_r0 + j * 4;
                *(bfrag*)&SKg[krow * 128 + ((k_ch ^ (krow & 15))) * 8] = kr[j];
                int vrow = v_r0 + j * 16;
                *(bfrag*)&SVg[vrow * 32 + ((v_ch ^ ((vrow + (vrow >> 2)) & 3))) * 8] = vr[j];
            }
            if (c + 1 < nc) {                // prefetch next; stays in flight across barrier
                const int nb = base + 64;
                #pragma unroll
                for (int j = 0; j < 2; ++j) {
                    kr[j] = *(const bfrag*)(Kb + (size_t)(nb + k_r0 + j * 4) * DH + k_ch * 8);
                    vr[j] = load_v_perm(Vb + (size_t)(v_r0 + j * 16) * T_SEQ + nb);
                }
            }
            __syncthreads();                 // staged data visible

            // QK^T (swapped): s2[t][kt][i] = S[k = base + kt*16 + quad*4 + i][q = q0 + t*16 + lr]
            ffrag s2[2][2] = {};
            #pragma unroll
            for (int kt = 0; kt < 2; ++kt)
                #pragma unroll
                for (int dc = 0; dc < 4; ++dc) {
                    bfrag kf = *(const bfrag*)&SKg[(kt * 16 + lr) * 128 + (((dc << 2) | quad) ^ lr) * 8];
                    s2[0][kt] = __builtin_amdgcn_mfma_f32_16x16x32_bf16(kf, qf[0][dc], s2[0][kt], 0, 0, 0);
                    s2[1][kt] = __builtin_amdgcn_mfma_f32_16x16x32_bf16(kf, qf[1][dc], s2[1][kt], 0, 0, 0);
                }

            // softmax numerator (static max); P built in-register (no LDS round-trip)
            const bool maskc = (c >= 2 * qb);
            bfrag pf[2];
            #pragma unroll
            for (int t = 0; t < 2; ++t) {
                const int qa = q0 + t * 16 + lr;
                float ev[2][4];
                #pragma unroll
                for (int kt = 0; kt < 2; ++kt)
                    #pragma unroll
                    for (int i = 0; i < 4; ++i) {
                        const int ka = base + kt * 16 + quad * 4 + i;
                        float e = (!maskc || ka <= qa) ? __expf(fmaf(s2[t][kt][i], scale, -16.0f)) : 0.0f;
                        lp[t] += e;
                        ev[kt][i] = e;
                    }
                union { unsigned u[4]; bfrag f; } pu;
                pu.u[0] = cvt_pk_bf16(ev[0][0], ev[0][1]);
                pu.u[1] = cvt_pk_bf16(ev[0][2], ev[0][3]);
                pu.u[2] = cvt_pk_bf16(ev[1][0], ev[1][1]);
                pu.u[3] = cvt_pk_bf16(ev[1][2], ev[1][3]);
                pf[t] = pu.f;
            }

            // P.V: pf is the A-fragment directly (k-order matches V's slot permutation)
            #pragma unroll
            for (int dt = 0; dt < 8; ++dt) {
                bfrag vf = *(const bfrag*)&SVg[(dt * 16 + lr) * 32 + ((quad ^ vsw)) * 8];
                o[0][dt] = __builtin_amdgcn_mfma_f32_16x16x32_bf16(pf[0], vf, o[0][dt], 0, 0, 0);
                o[1][dt] = __builtin_amdgcn_mfma_f32_16x16x32_bf16(pf[1], vf, o[1][dt], 0, 0, 0);
            }
        }

        // merge groups (fp32, two rounds to fit LDS) + epilogue by group 0
        __syncthreads();
        #pragma unroll
        for (int t = 0; t < 2; ++t) {
            if (g == 1) {
                #pragma unroll
                for (int d = 0; d < 8; ++d) shm.MRG[(d * 4 + wl) * 64 + lane] = o[t][d];
                ffrag l4 = {lp[t], 0.0f, 0.0f, 0.0f};
                shm.MRG[(8 * 4 + wl) * 64 + lane] = l4;
            }
            __syncthreads();
            if (g == 0) {
                #pragma unroll
                for (int d = 0; d < 8; ++d) o[t][d] += shm.MRG[(d * 4 + wl) * 64 + lane];
                float lsum = lp[t] + shm.MRG[(8 * 4 + wl) * 64 + lane][0];
                lsum += __shfl_xor(lsum, 16);
                lsum += __shfl_xor(lsum, 32);         // total l for q = lr, all quads
                float inv[4];
                #pragma unroll
                for (int i = 0; i < 4; ++i)
                    inv[i] = 1.0f / __shfl(lsum, quad * 4 + i);   // l for q = quad*4+i
                #pragma unroll
                for (int dt = 0; dt < 8; ++dt)
                    #pragma unroll
                    for (int i = 0; i < 4; ++i) {
                        int row = q0 + t * 16 + quad * 4 + i;
                        Y[((size_t)(b * T_SEQ) + row) * CDIM + h * DH + dt * 16 + lr] =
                            __float2bfloat16(o[t][dt][i] * inv[i]);
                    }
            }
            __syncthreads();                 // protect MRG before next round / next pass
        }
    }
}

extern "C" void kernel_launch(void* const* d_in, const int* in_sizes, int n_in,
                              void* d_out, int out_size, void* d_ws, size_t ws_size,
                              hipStream_t stream) {
    const float* x     = (const float*)d_in[0];
    const float* Wq    = (const float*)d_in[1];
    const float* Wkv   = (const float*)d_in[2];
    const float* Wproj = (const float*)d_in[3];
    float* out = (float*)d_out;

    char* ws = (char*)d_ws;
    size_t off = 0;
    auto alloc = [&](size_t bytes) { void* p = ws + off; off += (bytes + 255) & ~255ULL; return p; };
    bf16* xb   = (bf16*)alloc((size_t)BATCH * T_SEQ * CDIM * 2);
    bf16* wqb  = (bf16*)alloc((size_t)CDIM * CDIM * 2);
    bf16* wkvb = (bf16*)alloc((size_t)2 * NKV * DH * CDIM * 2);
    bf16* wpb  = (bf16*)alloc((size_t)CDIM * CDIM * 2);
    bf16* qb   = (bf16*)alloc((size_t)BATCH * NH * T_SEQ * DH * 2);
    bf16* kb   = (bf16*)alloc((size_t)BATCH * NKV * T_SEQ * DH * 2);
    bf16* vtb  = (bf16*)alloc((size_t)BATCH * NKV * DH * T_SEQ * 2);
    bf16* y1   = (bf16*)alloc((size_t)BATCH * T_SEQ * CDIM * 2);

    const int total4 = N4_X + N4_WQ + N4_WKV + N4_WP;
    cast_all<<<(total4 + 255) / 256, 256, 0, stream>>>(x, Wq, Wkv, Wproj, xb, wqb, wkvb, wpb);

    gemm_qkv<<<dim3(32, 24), 256, 0, stream>>>(xb, wqb, wkvb, qb, kb, vtb);
    normrope_k<<<(QROWS + KROWS) / 4, 256, 0, stream>>>(qb, kb);
    attn_k<<<dim3(8, NH, BATCH), 512, 0, stream>>>(qb, kb, vtb, y1);
    gemm_proj<<<dim3(32, 16), 256, 0, stream>>>(y1, wpb, out);
}